// Round 6
// baseline (185.144 us; speedup 1.0000x reference)
//
#include <hip/hip_runtime.h>

typedef short short8 __attribute__((ext_vector_type(8)));
typedef float f32x4 __attribute__((ext_vector_type(4)));

#define NE 1024
#define D 64
#define HW 4096
#define NTOK 65536
#define MARGIN 4.0e-3f
#define FLT_MAX_F 3.402823466e+38f

// ws: bn f32[1024]@0 ; ebf u16[65536]@4096 ; win u16[65536]@135168   (~262 KB)
#define WS_BN  0
#define WS_EBF 4096
#define WS_WIN 135168
// d_out overlay (exactly 16 MB): mask u64[65536*16] @0 ; frag short8[512*256*4] @8388608
// (k3 fully overwrites d_out afterwards; prep fully rewrites both regions each call)

__device__ __forceinline__ unsigned short f2bf(float f) {   // RNE f32->bf16
    unsigned u = __float_as_uint(f);
    return (unsigned short)((u + 0x7fffu + ((u >> 16) & 1u)) >> 16);
}

// numpy pairwise sum of squares, n=64 (frozen — exact since R2)
__device__ __forceinline__ float np_sum64_sq(const float* v) {
    float s[8];
#pragma unroll
    for (int j = 0; j < 8; ++j) s[j] = __fmul_rn(v[j], v[j]);
#pragma unroll
    for (int i = 8; i < 64; i += 8) {
#pragma unroll
        for (int j = 0; j < 8; ++j)
            s[j] = __fadd_rn(s[j], __fmul_rn(v[i + j], v[i + j]));
    }
    return __fadd_rn(__fadd_rn(__fadd_rn(s[0], s[1]), __fadd_rn(s[2], s[3])),
                     __fadd_rn(__fadd_rn(s[4], s[5]), __fadd_rn(s[6], s[7])));
}

__global__ __launch_bounds__(256) void kP_prep(
        const float* __restrict__ in, const float* __restrict__ cb,
        float* __restrict__ bn, unsigned short* __restrict__ ebf,
        unsigned long long* __restrict__ mask, short8* __restrict__ frag) {
    const int bid = blockIdx.x, tid = threadIdx.x;
    const int gid = bid * 256 + tid;            // 131072 threads
    // zero the 8 MB mask (64 B/thread, coalesced)
    {
        int4 z = {0, 0, 0, 0};
        int4* mz = (int4*)mask;
#pragma unroll
        for (int i = 0; i < 4; ++i) mz[(size_t)gid * 4 + i] = z;
    }
    if (gid < NE * D) ebf[gid] = f2bf(cb[gid]);
    if (gid < NE) {
        float row[D];
        const float4* r4 = reinterpret_cast<const float4*>(cb + (size_t)gid * D);
#pragma unroll
        for (int i = 0; i < 16; ++i) {
            float4 v = r4[i];
            row[4*i+0] = v.x; row[4*i+1] = v.y; row[4*i+2] = v.z; row[4*i+3] = v.w;
        }
        bn[gid] = np_sum64_sq(row);
    }
    // B-fragment build (layout verified exact in R4/R5), stored for k1 reuse
    const int w = tid >> 6, lane = tid & 63, lcol = lane & 15, lhi = lane >> 4;
    const int tokw = bid * 128 + w * 32;
    const int b = tokw >> 12, hwb = tokw & 4095;
    const float* xbase = in + (size_t)b * (D * HW);
    const int hw0 = hwb + lcol, hw1 = hwb + 16 + lcol;
    const int kb = lhi * 8;
    short8 B00, B01, B10, B11;
    const float* p;
    p = xbase + (size_t)kb * HW + hw0;
#pragma unroll
    for (int j = 0; j < 8; ++j) B00[j] = (short)f2bf(p[(size_t)j * HW]);
    p = xbase + (size_t)(kb + 32) * HW + hw0;
#pragma unroll
    for (int j = 0; j < 8; ++j) B01[j] = (short)f2bf(p[(size_t)j * HW]);
    p = xbase + (size_t)kb * HW + hw1;
#pragma unroll
    for (int j = 0; j < 8; ++j) B10[j] = (short)f2bf(p[(size_t)j * HW]);
    p = xbase + (size_t)(kb + 32) * HW + hw1;
#pragma unroll
    for (int j = 0; j < 8; ++j) B11[j] = (short)f2bf(p[(size_t)j * HW]);
    short8* fp = frag + ((size_t)bid * 256 + tid) * 4;
    fp[0] = B00; fp[1] = B01; fp[2] = B10; fp[3] = B11;
}

__global__ __launch_bounds__(256, 8) void k1_score(
        const unsigned short* __restrict__ ebf, const float* __restrict__ bn_g,
        const short8* __restrict__ frag, unsigned long long* __restrict__ mask) {
    __shared__ unsigned short ebq[128 * 64];   // 16 KiB: one 128-code chunk, swizzled
    __shared__ float sbn[128];

    const int tid  = threadIdx.x;
    const int tg   = blockIdx.x >> 3;          // token group (frag reuse across chunks)
    const int c    = blockIdx.x & 7;           // codebook chunk
    const int lane = tid & 63, w = tid >> 6;
    const int lcol = lane & 15, lhi = lane >> 4, lrow = lhi * 4;
    const int tokw = tg * 128 + w * 32;

    if (tid < 128) sbn[tid] = bn_g[c * 128 + tid];
    // stage chunk, XOR-swizzled (verified: 0 bank conflicts in R4/R5)
    const char* src = (const char*)(ebf + (size_t)c * 128 * 64);
#pragma unroll
    for (int i = 0; i < 4; ++i) {
        int L = (tid + i * 256) * 16;
        int row = L >> 7, wi = L & 127;
        int4 v = *(const int4*)(src + L);
        *(int4*)((char*)ebq + row * 128 + (wi ^ ((row & 7) << 4))) = v;
    }
    const short8* fp = frag + ((size_t)tg * 256 + tid) * 4;
    short8 B00 = fp[0], B01 = fp[1], B10 = fp[2], B11 = fp[3];
    __syncthreads();

    const int swz   = (lcol & 7) << 4;
    const int aoff0 = lcol * 128 + ((lhi * 16) ^ swz);
    const int aoff1 = lcol * 128 + ((64 + lhi * 16) ^ swz);

    // ---- pass A: chunk-local per-token min ----
    float v10 = FLT_MAX_F, v11 = FLT_MAX_F;
#pragma unroll
    for (int ct = 0; ct < 8; ++ct) {
        const char* lp = (const char*)ebq + ct * 2048;
        short8 A0 = *(const short8*)(lp + aoff0);
        short8 A1 = *(const short8*)(lp + aoff1);
        f32x4 bnv = *(const f32x4*)(sbn + ct * 16 + lrow);
        f32x4 acc = {0.f, 0.f, 0.f, 0.f};
        acc = __builtin_amdgcn_mfma_f32_16x16x32_bf16(A0, B00, acc, 0, 0, 0);
        acc = __builtin_amdgcn_mfma_f32_16x16x32_bf16(A1, B01, acc, 0, 0, 0);
#pragma unroll
        for (int r = 0; r < 4; ++r) v10 = fminf(v10, __fmaf_rn(-2.0f, acc[r], bnv[r]));
        f32x4 ac2 = {0.f, 0.f, 0.f, 0.f};
        ac2 = __builtin_amdgcn_mfma_f32_16x16x32_bf16(A0, B10, ac2, 0, 0, 0);
        ac2 = __builtin_amdgcn_mfma_f32_16x16x32_bf16(A1, B11, ac2, 0, 0, 0);
#pragma unroll
        for (int r = 0; r < 4; ++r) v11 = fminf(v11, __fmaf_rn(-2.0f, ac2[r], bnv[r]));
    }
    v10 = fminf(v10, __shfl_xor(v10, 16)); v10 = fminf(v10, __shfl_xor(v10, 32));
    v11 = fminf(v11, __shfl_xor(v11, 16)); v11 = fminf(v11, __shfl_xor(v11, 32));
    // chunk-local margin is sufficient: if np-winner k* in this chunk had
    // t(k*) > chunkmin + M (M >= 2*bf16err), the chunk would hold k' with
    // exact q(k') < q(k*) -- contradiction. Superset guaranteed.
    const float thr0 = v10 + MARGIN, thr1 = v11 + MARGIN;
    unsigned long long* mrow0 = mask + (size_t)(tokw + lcol) * 16;
    unsigned long long* mrow1 = mask + (size_t)(tokw + 16 + lcol) * 16;

    // ---- pass B: recompute (bit-identical), mark candidates ----
#pragma unroll
    for (int ct = 0; ct < 8; ++ct) {
        const char* lp = (const char*)ebq + ct * 2048;
        short8 A0 = *(const short8*)(lp + aoff0);
        short8 A1 = *(const short8*)(lp + aoff1);
        f32x4 bnv = *(const f32x4*)(sbn + ct * 16 + lrow);
        f32x4 acc = {0.f, 0.f, 0.f, 0.f};
        acc = __builtin_amdgcn_mfma_f32_16x16x32_bf16(A0, B00, acc, 0, 0, 0);
        acc = __builtin_amdgcn_mfma_f32_16x16x32_bf16(A1, B01, acc, 0, 0, 0);
        f32x4 ac2 = {0.f, 0.f, 0.f, 0.f};
        ac2 = __builtin_amdgcn_mfma_f32_16x16x32_bf16(A0, B10, ac2, 0, 0, 0);
        ac2 = __builtin_amdgcn_mfma_f32_16x16x32_bf16(A1, B11, ac2, 0, 0, 0);
        const int kg = c * 128 + ct * 16 + lrow;
#pragma unroll
        for (int r = 0; r < 4; ++r) {
            float t0 = __fmaf_rn(-2.0f, acc[r], bnv[r]);
            if (t0 <= thr0) atomicOr(&mrow0[(kg + r) >> 6], 1ull << ((kg + r) & 63));
            float t1 = __fmaf_rn(-2.0f, ac2[r], bnv[r]);
            if (t1 <= thr1) atomicOr(&mrow1[(kg + r) >> 6], 1ull << ((kg + r) & 63));
        }
    }
}

__global__ __launch_bounds__(256, 4) void k2_rerank(
        const float* __restrict__ in, const float* __restrict__ cb,
        const float* __restrict__ bn, const unsigned long long* __restrict__ mask,
        unsigned short* __restrict__ win) {
    const int tok = blockIdx.x * 256 + threadIdx.x;
    const int b = tok >> 12, hw = tok & 4095;

    unsigned long long m[16];
    int tot = 0;
#pragma unroll
    for (int i = 0; i < 16; ++i) { m[i] = mask[(size_t)tok * 16 + i]; tot += (int)__popcll(m[i]); }
    if (tot == 1) {
        int kk = 0;
#pragma unroll
        for (int i = 0; i < 16; ++i) if (m[i]) kk = i * 64 + (int)__builtin_ctzll(m[i]);
        win[tok] = (unsigned short)kk;
        return;
    }

    const float* x = in + (size_t)b * (D * HW) + hw;
    float xv[D];
#pragma unroll
    for (int d = 0; d < D; ++d) xv[d] = x[(size_t)d * HW];
    const float a = np_sum64_sq(xv);                 // frozen

    float bestq = FLT_MAX_F;
    int   bestk = 0;
#pragma unroll
    for (int wd = 0; wd < 16; ++wd) {                // ascending word/bit -> ascending k
        unsigned long long mm = m[wd];
        while (mm) {
            int bit = (int)__builtin_ctzll(mm);
            mm &= mm - 1;
            int k = wd * 64 + bit;
            const float* er = cb + (size_t)k * D;
            float dot = 0.f;                         // frozen: sequential, ascending d
#pragma unroll
            for (int d = 0; d < D; ++d) dot = __fmaf_rn(xv[d], er[d], dot);
            float qv = __fsub_rn(__fadd_rn(a, bn[k]), __fmul_rn(2.0f, dot));  // frozen
            if (qv < bestq) { bestq = qv; bestk = k; }   // strict < : first-min
        }
    }
    win[tok] = (unsigned short)bestk;
}

__global__ void k3_gather(const float* __restrict__ cb,
                          const unsigned short* __restrict__ win,
                          float* __restrict__ out) {
    const int tok = blockIdx.x * 256 + threadIdx.x;
    const int b = tok >> 12, hw = tok & 4095;
    const unsigned k = win[tok];
    float* ot = out + (size_t)b * (D * HW) + hw;
    const float4* er = reinterpret_cast<const float4*>(cb + (size_t)k * D);
#pragma unroll
    for (int i = 0; i < 16; ++i) {
        float4 e = er[i];
        ot[(size_t)(4*i+0) * HW] = e.x;
        ot[(size_t)(4*i+1) * HW] = e.y;
        ot[(size_t)(4*i+2) * HW] = e.z;
        ot[(size_t)(4*i+3) * HW] = e.w;
    }
}

extern "C" void kernel_launch(void* const* d_in, const int* in_sizes, int n_in,
                              void* d_out, int out_size, void* d_ws, size_t ws_size,
                              hipStream_t stream) {
    const float* in  = (const float*)d_in[0];
    const float* cb  = (const float*)d_in[1];
    float*       out = (float*)d_out;
    char*        ws  = (char*)d_ws;

    float*              bn   = (float*)(ws + WS_BN);
    unsigned short*     ebf  = (unsigned short*)(ws + WS_EBF);
    unsigned short*     win  = (unsigned short*)(ws + WS_WIN);
    unsigned long long* mask = (unsigned long long*)d_out;
    short8*             frag = (short8*)((char*)d_out + 8388608);

    hipLaunchKernelGGL(kP_prep,   dim3(512),  dim3(256), 0, stream, in, cb, bn, ebf, mask, frag);
    hipLaunchKernelGGL(k1_score,  dim3(4096), dim3(256), 0, stream, ebf, bn, frag, mask);
    hipLaunchKernelGGL(k2_rerank, dim3(256),  dim3(256), 0, stream, in, cb, bn, mask, win);
    hipLaunchKernelGGL(k3_gather, dim3(256),  dim3(256), 0, stream, cb, win, out);
}

// Round 7
// 179.788 us; speedup vs baseline: 1.0298x; 1.0298x over previous
//
#include <hip/hip_runtime.h>

typedef short short8 __attribute__((ext_vector_type(8)));
typedef float f32x4 __attribute__((ext_vector_type(4)));
typedef unsigned long long u64;

#define NE 1024
#define D 64
#define HW 4096
#define NTOK 65536
#define MARGIN 4.0e-3f
#define FLT_MAX_F 3.402823466e+38f

// ws: bn f32[1024]@0 ; ebf u16[65536]@4096 ; win u16[65536]@135168
#define WS_BN  0
#define WS_EBF 4096
#define WS_WIN 135168
// d_out overlay (16 MB): mask u64[65536*16] @0 ; frag short8[524288] @8388608

__device__ __forceinline__ unsigned short f2bf(float f) {   // RNE f32->bf16
    unsigned u = __float_as_uint(f);
    return (unsigned short)((u + 0x7fffu + ((u >> 16) & 1u)) >> 16);
}

// numpy pairwise sum of squares, n=64 (frozen — exact since R2)
__device__ __forceinline__ float np_sum64_sq(const float* v) {
    float s[8];
#pragma unroll
    for (int j = 0; j < 8; ++j) s[j] = __fmul_rn(v[j], v[j]);
#pragma unroll
    for (int i = 8; i < 64; i += 8) {
#pragma unroll
        for (int j = 0; j < 8; ++j)
            s[j] = __fadd_rn(s[j], __fmul_rn(v[i + j], v[i + j]));
    }
    return __fadd_rn(__fadd_rn(__fadd_rn(s[0], s[1]), __fadd_rn(s[2], s[3])),
                     __fadd_rn(__fadd_rn(s[4], s[5]), __fadd_rn(s[6], s[7])));
}

__global__ __launch_bounds__(256) void kP_prep(
        const float* __restrict__ in, const float* __restrict__ cb,
        float* __restrict__ bn, unsigned short* __restrict__ ebf,
        u64* __restrict__ mask, short8* __restrict__ frag) {
    const int gid = blockIdx.x * 256 + threadIdx.x;     // 524288 threads
    ((int4*)mask)[gid] = int4{0, 0, 0, 0};              // zero 8 MB mask
    if (gid < NE * D) ebf[gid] = f2bf(cb[gid]);
    if (gid < NE) {
        float row[D];
        const float4* r4 = reinterpret_cast<const float4*>(cb + (size_t)gid * D);
#pragma unroll
        for (int i = 0; i < 16; ++i) {
            float4 v = r4[i];
            row[4*i+0] = v.x; row[4*i+1] = v.y; row[4*i+2] = v.z; row[4*i+3] = v.w;
        }
        bn[gid] = np_sum64_sq(row);
    }
    // one B-fragment per thread (layout identical to R4-R6 proven build)
    const int slot = gid >> 2, j = gid & 3;
    const int tid_o = slot & 255, tg = slot >> 8;
    const int w = tid_o >> 6, lane = tid_o & 63;
    const int lcol = lane & 15, lhi = lane >> 4;
    const int tokw = tg * 128 + w * 32;
    const int b = tokw >> 12, hwb = tokw & 4095;
    const int hw = hwb + ((j & 2) ? 16 : 0) + lcol;
    const int kb = lhi * 8 + ((j & 1) ? 32 : 0);
    const float* p = in + (size_t)b * (D * HW) + (size_t)kb * HW + hw;
    short8 B;
#pragma unroll
    for (int j2 = 0; j2 < 8; ++j2) B[j2] = (short)f2bf(p[(size_t)j2 * HW]);
    frag[gid] = B;
}

__global__ __launch_bounds__(256, 4) void k1_score(
        const unsigned short* __restrict__ ebf, const float* __restrict__ bn_g,
        const short8* __restrict__ frag, u64* __restrict__ mask) {
    __shared__ unsigned short ebq[128 * 64];   // 16 KiB, XOR-swizzled (proven)
    __shared__ float sbn[128];

    const int tid  = threadIdx.x;
    const int tg   = blockIdx.x >> 3;
    const int c    = blockIdx.x & 7;
    const int lane = tid & 63, w = tid >> 6;
    const int lcol = lane & 15, lhi = lane >> 4, lrow = lhi * 4;
    const int tokw = tg * 128 + w * 32;

    if (tid < 128) sbn[tid] = bn_g[c * 128 + tid];
    const char* src = (const char*)(ebf + (size_t)c * 128 * 64);
#pragma unroll
    for (int i = 0; i < 4; ++i) {
        int L = (tid + i * 256) * 16;
        int row = L >> 7, wi = L & 127;
        int4 v = *(const int4*)(src + L);
        *(int4*)((char*)ebq + row * 128 + (wi ^ ((row & 7) << 4))) = v;
    }
    const short8* fp = frag + ((size_t)tg * 256 + tid) * 4;
    short8 B00 = fp[0], B01 = fp[1], B10 = fp[2], B11 = fp[3];
    __syncthreads();

    const int swz   = (lcol & 7) << 4;
    const int aoff0 = lcol * 128 + ((lhi * 16) ^ swz);
    const int aoff1 = lcol * 128 + ((64 + lhi * 16) ^ swz);

    // single MFMA pass; keep all t-values in registers (constant-indexed)
    float t0a[32], t1a[32];
    float v10 = FLT_MAX_F, v11 = FLT_MAX_F;
#pragma unroll
    for (int ct = 0; ct < 8; ++ct) {
        const char* lp = (const char*)ebq + ct * 2048;
        short8 A0 = *(const short8*)(lp + aoff0);
        short8 A1 = *(const short8*)(lp + aoff1);
        f32x4 bnv = *(const f32x4*)(sbn + ct * 16 + lrow);
        f32x4 acc = {0.f, 0.f, 0.f, 0.f};
        acc = __builtin_amdgcn_mfma_f32_16x16x32_bf16(A0, B00, acc, 0, 0, 0);
        acc = __builtin_amdgcn_mfma_f32_16x16x32_bf16(A1, B01, acc, 0, 0, 0);
        f32x4 ac2 = {0.f, 0.f, 0.f, 0.f};
        ac2 = __builtin_amdgcn_mfma_f32_16x16x32_bf16(A0, B10, ac2, 0, 0, 0);
        ac2 = __builtin_amdgcn_mfma_f32_16x16x32_bf16(A1, B11, ac2, 0, 0, 0);
#pragma unroll
        for (int r = 0; r < 4; ++r) {
            float t0 = __fmaf_rn(-2.0f, acc[r], bnv[r]);
            t0a[ct * 4 + r] = t0; v10 = fminf(v10, t0);
            float t1 = __fmaf_rn(-2.0f, ac2[r], bnv[r]);
            t1a[ct * 4 + r] = t1; v11 = fminf(v11, t1);
        }
    }
    v10 = fminf(v10, __shfl_xor(v10, 16)); v10 = fminf(v10, __shfl_xor(v10, 32));
    v11 = fminf(v11, __shfl_xor(v11, 16)); v11 = fminf(v11, __shfl_xor(v11, 32));
    // chunk-local margin superset proof: M >= 2*bf16err (see R6) — frozen
    const float thr0 = v10 + MARGIN, thr1 = v11 + MARGIN;
    u64* mrow0 = mask + (size_t)(tokw + lcol) * 16;
    u64* mrow1 = mask + (size_t)(tokw + 16 + lcol) * 16;
#pragma unroll
    for (int i = 0; i < 32; ++i) {
        const int kg = c * 128 + (i >> 2) * 16 + lrow + (i & 3);
        if (t0a[i] <= thr0) atomicOr(&mrow0[kg >> 6], 1ull << (kg & 63));
        if (t1a[i] <= thr1) atomicOr(&mrow1[kg >> 6], 1ull << (kg & 63));
    }
}

// wave per token, lane per candidate; frozen numerics via shuffle-broadcast x
__global__ __launch_bounds__(256, 4) void k2_rerank(
        const float* __restrict__ in, const float* __restrict__ cb,
        const float* __restrict__ bn, const u64* __restrict__ mask,
        unsigned short* __restrict__ win) {
    const int tid  = threadIdx.x;
    const int lane = tid & 63;
    const int tok  = blockIdx.x * 4 + (tid >> 6);
    const int b = tok >> 12, hw = tok & 4095;

    u64 myw = (lane < 16) ? mask[(size_t)tok * 16 + lane] : 0ull;
    int mycnt = __popcll(myw);

    const float xl = in[(size_t)b * (D * HW) + (size_t)lane * HW + hw];  // lane d holds x_d

    u64 best = ~0ull;
    int total;
    for (int base = 0; ; base += 64) {
        const int i = base + lane;
        int word = -1, rank = 0, off = 0;
#pragma unroll
        for (int u = 0; u < 16; ++u) {
            int cu = __shfl(mycnt, u);
            if (word < 0 && i < off + cu) { word = u; rank = i - off; }
            off += cu;
        }
        total = off;
        const bool active = (word >= 0);
        u64 mw = __shfl(myw, active ? word : 0);
        for (int r = 0; r < rank; ++r) mw &= mw - 1;
        const int k = active ? (word * 64 + (int)__builtin_ctzll(mw)) : 0;

        const float4* e4 = reinterpret_cast<const float4*>(cb + (size_t)k * D);
        float4 e[16];
#pragma unroll
        for (int q = 0; q < 16; ++q) e[q] = e4[q];
        const float bnk = bn[k];

        float s0=0.f,s1=0.f,s2=0.f,s3=0.f,s4=0.f,s5=0.f,s6=0.f,s7=0.f;
        float dot = 0.f;
#pragma unroll
        for (int d = 0; d < 64; ++d) {
            const float xd = __shfl(xl, d);
            const float ed = (d & 3) == 0 ? e[d >> 2].x : (d & 3) == 1 ? e[d >> 2].y
                           : (d & 3) == 2 ? e[d >> 2].z : e[d >> 2].w;
            dot = __fmaf_rn(xd, ed, dot);               // frozen: sequential asc d
            const float x2 = __fmul_rn(xd, xd);         // frozen np-pairwise (0+x2==x2)
            switch (d & 7) {
                case 0: s0 = __fadd_rn(s0, x2); break;
                case 1: s1 = __fadd_rn(s1, x2); break;
                case 2: s2 = __fadd_rn(s2, x2); break;
                case 3: s3 = __fadd_rn(s3, x2); break;
                case 4: s4 = __fadd_rn(s4, x2); break;
                case 5: s5 = __fadd_rn(s5, x2); break;
                case 6: s6 = __fadd_rn(s6, x2); break;
                default: s7 = __fadd_rn(s7, x2); break;
            }
        }
        const float a = __fadd_rn(__fadd_rn(__fadd_rn(s0, s1), __fadd_rn(s2, s3)),
                                  __fadd_rn(__fadd_rn(s4, s5), __fadd_rn(s6, s7)));
        const float qv = __fsub_rn(__fadd_rn(a, bnk), __fmul_rn(2.0f, dot));  // frozen
        if (active) {
            u64 key = (((u64)__float_as_uint(qv)) << 32) | (unsigned)k;  // q>0 always
            best = best < key ? best : key;
        }
        if (base + 64 >= total) break;
    }
#pragma unroll
    for (int o = 32; o; o >>= 1) {
        u64 v = __shfl_xor(best, o);
        best = best < v ? best : v;
    }
    if (lane == 0) win[tok] = (unsigned short)(best & 0x3FFull);
}

__global__ __launch_bounds__(256) void k3_gather(
        const float* __restrict__ cb, const unsigned short* __restrict__ win,
        float* __restrict__ out) {
    const int gid = blockIdx.x * 256 + threadIdx.x;   // 262144 threads
    const int tok = gid >> 2, qd = (gid & 3) << 4;
    const int b = tok >> 12, hw = tok & 4095;
    const unsigned k = win[tok];
    const float4* er = reinterpret_cast<const float4*>(cb + (size_t)k * D + qd);
    float* ot = out + (size_t)b * (D * HW) + hw;
#pragma unroll
    for (int i = 0; i < 4; ++i) {
        float4 e = er[i];
        ot[(size_t)(qd + 4*i + 0) * HW] = e.x;
        ot[(size_t)(qd + 4*i + 1) * HW] = e.y;
        ot[(size_t)(qd + 4*i + 2) * HW] = e.z;
        ot[(size_t)(qd + 4*i + 3) * HW] = e.w;
    }
}

extern "C" void kernel_launch(void* const* d_in, const int* in_sizes, int n_in,
                              void* d_out, int out_size, void* d_ws, size_t ws_size,
                              hipStream_t stream) {
    const float* in  = (const float*)d_in[0];
    const float* cb  = (const float*)d_in[1];
    float*       out = (float*)d_out;
    char*        ws  = (char*)d_ws;

    float*          bn   = (float*)(ws + WS_BN);
    unsigned short* ebf  = (unsigned short*)(ws + WS_EBF);
    unsigned short* win  = (unsigned short*)(ws + WS_WIN);
    u64*            mask = (u64*)d_out;
    short8*         frag = (short8*)((char*)d_out + 8388608);

    hipLaunchKernelGGL(kP_prep,   dim3(2048),  dim3(256), 0, stream, in, cb, bn, ebf, mask, frag);
    hipLaunchKernelGGL(k1_score,  dim3(4096),  dim3(256), 0, stream, ebf, bn, frag, mask);
    hipLaunchKernelGGL(k2_rerank, dim3(16384), dim3(256), 0, stream, in, cb, bn, mask, win);
    hipLaunchKernelGGL(k3_gather, dim3(1024),  dim3(256), 0, stream, cb, win, out);
}